// Round 1
// baseline (285.984 us; speedup 1.0000x reference)
//
#include <hip/hip_runtime.h>
#include <hip/hip_bf16.h>
#include <stdint.h>

// SimpleSSM: y = (scan_t h=tanh(A*h + x@W_B^T + b_B)) @ W_C^T + b_C
// B=8, L=2048, D=1024.  All fp32 in/out.
// Strategy: bf16 MFMA GEMMs. GEMM1 in 3-term split-bf16 (safe vs recurrence
// error amplification), recurrence fp32-in-register with 32-deep prefetch,
// GEMM2 plain bf16.

using short8 = __attribute__((ext_vector_type(8))) short;   // 8 bf16
using f32x4  = __attribute__((ext_vector_type(4))) float;

#define DEV __device__ __forceinline__

DEV ushort f2bf_rn(float x) {
  uint32_t u = __float_as_uint(x);
  uint32_t r = (u + 0x7FFFu + ((u >> 16) & 1u)) >> 16;
  return (ushort)r;
}
DEV float bf2f(ushort b) { return __uint_as_float(((uint32_t)b) << 16); }

DEV void gload_lds16(const void* g, void* l) {
  __builtin_amdgcn_global_load_lds((const __attribute__((address_space(1))) void*)g,
                                   (__attribute__((address_space(3))) void*)l,
                                   16, 0, 0);
}

// ---------------- conversion kernels ----------------
__global__ void k_split_convert(const float* __restrict__ in, ushort* __restrict__ hi,
                                ushort* __restrict__ lo, int n4) {
  const int stride = gridDim.x * blockDim.x;
  for (int i = blockIdx.x * blockDim.x + threadIdx.x; i < n4; i += stride) {
    float4 v = reinterpret_cast<const float4*>(in)[i];
    ushort4 hv, lv;
    hv.x = f2bf_rn(v.x); lv.x = f2bf_rn(v.x - bf2f(hv.x));
    hv.y = f2bf_rn(v.y); lv.y = f2bf_rn(v.y - bf2f(hv.y));
    hv.z = f2bf_rn(v.z); lv.z = f2bf_rn(v.z - bf2f(hv.z));
    hv.w = f2bf_rn(v.w); lv.w = f2bf_rn(v.w - bf2f(hv.w));
    reinterpret_cast<ushort4*>(hi)[i] = hv;
    reinterpret_cast<ushort4*>(lo)[i] = lv;
  }
}

__global__ void k_convert(const float* __restrict__ in, ushort* __restrict__ hi, int n4) {
  const int stride = gridDim.x * blockDim.x;
  for (int i = blockIdx.x * blockDim.x + threadIdx.x; i < n4; i += stride) {
    float4 v = reinterpret_cast<const float4*>(in)[i];
    ushort4 hv;
    hv.x = f2bf_rn(v.x); hv.y = f2bf_rn(v.y);
    hv.z = f2bf_rn(v.z); hv.w = f2bf_rn(v.w);
    reinterpret_cast<ushort4*>(hi)[i] = hv;
  }
}

// ---------------- GEMM (C = A @ B^T + bias), A:[M,K] B:[N,K] bf16, C fp32 ----
// 128x128 tile, BK=64, 4 waves (2x2), each wave 64x64 via 4x4 16x16x32 MFMAs.
// LDS XOR-swizzle (byte ^= (row&7)<<4) applied via pre-swizzled global source
// (global_load_lds writes linearly) + swizzled ds_read address.
template <int SPLIT>
__global__ __launch_bounds__(256, 2)
void k_gemm_bt(const ushort* __restrict__ Ah, const ushort* __restrict__ Al,
               const ushort* __restrict__ Bh, const ushort* __restrict__ Bl,
               const float* __restrict__ bias, float* __restrict__ C,
               int M, int N, int K) {
  constexpr int NMAT = SPLIT ? 4 : 2;
  __shared__ __align__(1024) ushort lds[NMAT * 128 * 64];
  ushort* sAh = lds;
  ushort* sAl = lds + (SPLIT ? 8192 : 0);
  ushort* sBh = lds + (SPLIT ? 16384 : 8192);
  ushort* sBl = lds + (SPLIT ? 24576 : 8192);

  const int t = threadIdx.x;
  const int lane = t & 63;
  const int w = t >> 6;
  const int wm = w >> 1, wn = w & 1;
  const int bm = blockIdx.y, bn = blockIdx.x;
  const int lr = lane & 15;           // fragment row/col within 16
  const int lk = (lane >> 4) << 3;    // k offset 0/8/16/24

  const ushort* gA_h = Ah + (size_t)(bm * 128) * K;
  const ushort* gA_l = SPLIT ? (Al + (size_t)(bm * 128) * K) : gA_h;
  const ushort* gB_h = Bh + (size_t)(bn * 128) * K;
  const ushort* gB_l = SPLIT ? (Bl + (size_t)(bn * 128) * K) : gB_h;

  f32x4 acc[4][4];
#pragma unroll
  for (int i = 0; i < 4; ++i)
#pragma unroll
    for (int j = 0; j < 4; ++j)
#pragma unroll
      for (int r = 0; r < 4; ++r) acc[i][j][r] = 0.f;

  auto stage = [&](int kt) {
    const int k0 = kt * 64;
#pragma unroll
    for (int i = 0; i < 4; ++i) {
      const int lin16 = i * 256 + t;          // 16B-chunk index, linear in LDS
      const int lb = lin16 << 4;              // LDS byte offset
      const int row = lb >> 7;                // 128B (=64 bf16) per row
      const int srcb = (lb & 127) ^ ((row & 7) << 4);  // inverse swizzle on SOURCE
      const size_t goff = (size_t)row * K + (size_t)(k0 + (srcb >> 1));
      const int lidx = i * 2048 + w * 512;    // wave-uniform LDS base (ushort idx)
      gload_lds16(gA_h + goff, sAh + lidx);
      if (SPLIT) gload_lds16(gA_l + goff, sAl + lidx);
      gload_lds16(gB_h + goff, sBh + lidx);
      if (SPLIT) gload_lds16(gB_l + goff, sBl + lidx);
    }
  };

  auto ldfrag = [&](const ushort* s, int row, int kc) -> short8 {
    const int byte = (row << 7) + (((kc << 1) ^ ((row & 7) << 4)));
    return *reinterpret_cast<const short8*>(reinterpret_cast<const char*>(s) + byte);
  };

  const int NT = K / 64;
  stage(0);
  for (int kt = 0; kt < NT; ++kt) {
    __syncthreads();   // staged data visible (compiler drains vmcnt here)
#pragma unroll
    for (int kk = 0; kk < 2; ++kk) {
      short8 ah[4], bh[4], al[4], bl[4];
      const int kc = kk * 32 + lk;
#pragma unroll
      for (int i = 0; i < 4; ++i) {
        const int row = wm * 64 + i * 16 + lr;
        ah[i] = ldfrag(sAh, row, kc);
        if (SPLIT) al[i] = ldfrag(sAl, row, kc);
      }
#pragma unroll
      for (int j = 0; j < 4; ++j) {
        const int row = wn * 64 + j * 16 + lr;
        bh[j] = ldfrag(sBh, row, kc);
        if (SPLIT) bl[j] = ldfrag(sBl, row, kc);
      }
#pragma unroll
      for (int i = 0; i < 4; ++i)
#pragma unroll
        for (int j = 0; j < 4; ++j) {
          acc[i][j] = __builtin_amdgcn_mfma_f32_16x16x32_bf16(ah[i], bh[j], acc[i][j], 0, 0, 0);
          if (SPLIT) {
            acc[i][j] = __builtin_amdgcn_mfma_f32_16x16x32_bf16(al[i], bh[j], acc[i][j], 0, 0, 0);
            acc[i][j] = __builtin_amdgcn_mfma_f32_16x16x32_bf16(ah[i], bl[j], acc[i][j], 0, 0, 0);
          }
        }
    }
    __syncthreads();   // all reads done before overwrite
    if (kt + 1 < NT) stage(kt + 1);
  }

  // Epilogue: C/D layout col=lane&15, row=(lane>>4)*4+reg  [m89]
  float* Cb = C + (size_t)(bm * 128) * N + bn * 128;
#pragma unroll
  for (int i = 0; i < 4; ++i)
#pragma unroll
    for (int j = 0; j < 4; ++j) {
      const int col = wn * 64 + j * 16 + lr;
      const float bv = bias[bn * 128 + col];
#pragma unroll
      for (int r = 0; r < 4; ++r) {
        const int rowt = wm * 64 + i * 16 + ((lane >> 4) << 2) + r;
        Cb[(size_t)rowt * N + col] = acc[i][j][r] + bv;
      }
    }
}

// ---------------- sequential recurrence ----------------
// one thread per (b,d) channel; fp32 state; 32-deep register prefetch of Bx.
__global__ __launch_bounds__(64)
void k_recurrence(const float* __restrict__ Bx, const float* __restrict__ Avec,
                  ushort* __restrict__ Hout) {
  const int tid = blockIdx.x * 64 + threadIdx.x;   // 0..8191
  const int b = tid >> 10;
  const int d = tid & 1023;
  const float a = Avec[d];
  const float* bx = Bx + (size_t)b * 2048 * 1024 + d;
  ushort* ho = Hout + (size_t)b * 2048 * 1024 + d;

  constexpr int P = 32;
  constexpr int NC = 2048 / P;
  float buf[P];
#pragma unroll
  for (int i = 0; i < P; ++i) buf[i] = bx[(size_t)i * 1024];
  float h = 0.f;
  for (int c = 0; c < NC; ++c) {
    float nbuf[P];
    if (c + 1 < NC) {
#pragma unroll
      for (int i = 0; i < P; ++i) nbuf[i] = bx[(size_t)((c + 1) * P + i) * 1024];
    } else {
#pragma unroll
      for (int i = 0; i < P; ++i) nbuf[i] = 0.f;
    }
#pragma unroll
    for (int i = 0; i < P; ++i) {
      float u = fmaf(a, h, buf[i]);
      u = fminf(15.f, fmaxf(-15.f, u));
      const float p = __expf(u + u);                       // e^{2u}
      h = (p - 1.f) * __builtin_amdgcn_rcpf(p + 1.f);      // tanh(u)
      ho[(size_t)(c * P + i) * 1024] = f2bf_rn(h);
    }
#pragma unroll
    for (int i = 0; i < P; ++i) buf[i] = nbuf[i];
  }
}

// ---------------- launch ----------------
extern "C" void kernel_launch(void* const* d_in, const int* in_sizes, int n_in,
                              void* d_out, int out_size, void* d_ws, size_t ws_size,
                              hipStream_t stream) {
  const float* x   = (const float*)d_in[0];
  const float* A   = (const float*)d_in[1];
  const float* W_B = (const float*)d_in[2];
  const float* b_B = (const float*)d_in[3];
  const float* W_C = (const float*)d_in[4];
  const float* b_C = (const float*)d_in[5];
  float* y = (float*)d_out;

  const int Bsz = 8, L = 2048, D = 1024;
  const int M = Bsz * L;                       // 16384

  char* ws = (char*)d_ws;
  ushort* x_hi  = (ushort*)(ws);                        // 32MB
  ushort* x_lo  = (ushort*)(ws + 33554432);             // 32MB
  ushort* wb_hi = (ushort*)(ws + 67108864);             // 2MB
  ushort* wb_lo = (ushort*)(ws + 69206016);             // 2MB
  ushort* wc_h  = (ushort*)(ws + 71303168);             // 2MB
  float*  Bx    = (float*)(ws + 73400320);              // 64MB
  ushort* h     = x_hi;                                 // alias (x dead after GEMM1)

  k_split_convert<<<2048, 256, 0, stream>>>(x, x_hi, x_lo, M * D / 4);
  k_split_convert<<<1024, 256, 0, stream>>>(W_B, wb_hi, wb_lo, D * D / 4);
  k_convert<<<1024, 256, 0, stream>>>(W_C, wc_h, D * D / 4);

  k_gemm_bt<1><<<dim3(D / 128, M / 128), 256, 0, stream>>>(
      x_hi, x_lo, wb_hi, wb_lo, b_B, Bx, M, D, D);

  k_recurrence<<<(Bsz * D) / 64, 64, 0, stream>>>(Bx, A, h);

  k_gemm_bt<0><<<dim3(D / 128, M / 128), 256, 0, stream>>>(
      h, (const ushort*)nullptr, wc_h, (const ushort*)nullptr, b_C, y, M, D, D);
}

// Round 4
// 232.589 us; speedup vs baseline: 1.2296x; 1.2296x over previous
//
#include <hip/hip_runtime.h>
#include <hip/hip_bf16.h>
#include <stdint.h>

// SimpleSSM: y = (scan_t h=tanh(A*h + x@W_B^T + b_B)) @ W_C^T + b_C
// B=8, L=2048, D=1024.  All fp32 in/out.
// R4: GEMM1 = split-fp16 3-term (hi*hi + lo*hi + hi*lo). R2/R3 proved the
// scan chaotically amplifies GEMM1 quantization error (bf16 AND fp16 both
// saturate at 0.25); R1's split passed — split is mandatory. fp16 split
// residual ~2^-21. GEMM2 + h storage plain fp16 (linear-pass error only).
// XCD-bijective tile remap; recurrence 5-dep-op chain + ping-pong dbuf.

using half8 = __attribute__((ext_vector_type(8))) _Float16;  // 8 fp16
using f32x4 = __attribute__((ext_vector_type(4))) float;

#define DEV __device__ __forceinline__

#if __has_builtin(__builtin_amdgcn_exp2f)
DEV float pexp(float x) { return __builtin_amdgcn_exp2f(x); }
constexpr float BX_SCALE = 2.8853900817779268f;   // 2*log2(e): exp2 domain
#else
DEV float pexp(float x) { return __expf(x); }
constexpr float BX_SCALE = 2.0f;                   // e^x domain
#endif

DEV ushort f2h(float x) {
  union { _Float16 f; ushort u; } c;
  c.f = (_Float16)x;          // v_cvt_f16_f32, RNE
  return c.u;
}
DEV float h2f(ushort u) {
  union { ushort u; _Float16 f; } c;
  c.u = u;
  return (float)c.f;
}

DEV void gload_lds16(const void* g, void* l) {
  __builtin_amdgcn_global_load_lds((const __attribute__((address_space(1))) void*)g,
                                   (__attribute__((address_space(3))) void*)l,
                                   16, 0, 0);
}

// ---------------- conversion kernels ----------------
// fp32 -> fp16 hi + fp16 lo (lo = fp16(x - hi)); residual ~2^-22*|x|.
__global__ void k_split_convert(const float* __restrict__ in, ushort* __restrict__ hi,
                                ushort* __restrict__ lo, int n4) {
  const int stride = gridDim.x * blockDim.x;
  for (int i = blockIdx.x * blockDim.x + threadIdx.x; i < n4; i += stride) {
    float4 v = reinterpret_cast<const float4*>(in)[i];
    ushort4 hv, lv;
    hv.x = f2h(v.x); lv.x = f2h(v.x - h2f(hv.x));
    hv.y = f2h(v.y); lv.y = f2h(v.y - h2f(hv.y));
    hv.z = f2h(v.z); lv.z = f2h(v.z - h2f(hv.z));
    hv.w = f2h(v.w); lv.w = f2h(v.w - h2f(hv.w));
    reinterpret_cast<ushort4*>(hi)[i] = hv;
    reinterpret_cast<ushort4*>(lo)[i] = lv;
  }
}

__global__ void k_convert(const float* __restrict__ in, ushort* __restrict__ out, int n4) {
  const int stride = gridDim.x * blockDim.x;
  for (int i = blockIdx.x * blockDim.x + threadIdx.x; i < n4; i += stride) {
    float4 v = reinterpret_cast<const float4*>(in)[i];
    ushort4 hv;
    hv.x = f2h(v.x); hv.y = f2h(v.y);
    hv.z = f2h(v.z); hv.w = f2h(v.w);
    reinterpret_cast<ushort4*>(out)[i] = hv;
  }
}

// ---------------- GEMM (C = scale*(A @ B^T + bias)), A:[M,K] B:[N,K] fp16 ---
// 128x128 tile, BK=64, 4 waves (2x2), each wave 64x64 via 4x4 16x16x32 MFMAs.
// SPLIT: acc += Ah*Bh + Al*Bh + Ah*Bl (3 MFMAs). LDS XOR-swizzle via
// pre-swizzled global source + swizzled ds_read (rule #21). XCD-bijective
// remap: xcd owns bm ≡ xcd (mod 8); weight panel L2-resident per XCD.
template <int SPLIT, int SCALE>
__global__ __launch_bounds__(256, 2)
void k_gemm_bt(const ushort* __restrict__ Ah, const ushort* __restrict__ Al,
               const ushort* __restrict__ Bh, const ushort* __restrict__ Bl,
               const float* __restrict__ bias, float* __restrict__ C,
               int M, int N, int K) {
  constexpr int NMAT = SPLIT ? 4 : 2;
  __shared__ __align__(1024) ushort lds[NMAT * 128 * 64];
  ushort* sAh = lds;
  ushort* sAl = lds + (SPLIT ? 8192 : 0);
  ushort* sBh = lds + (SPLIT ? 16384 : 8192);
  ushort* sBl = lds + (SPLIT ? 24576 : 8192);

  const int t = threadIdx.x;
  const int lane = t & 63;
  const int w = t >> 6;
  const int wm = w >> 1, wn = w & 1;

  // XCD-bijective remap (grid 8 x 128): l = linear id, xcd = l&7 (round-robin
  // dispatch), s = l>>3; bm = (s&~7)|xcd, bn = s&7.  Bijective: inverse is
  // xcd=bm&7, s=(bm&~7)|bn, l=8s+xcd.
  int bm, bn;
  if (gridDim.x == 8) {
    const int l = blockIdx.y * 8 + blockIdx.x;
    const int xcd = l & 7, s = l >> 3;
    bm = ((s >> 3) << 3) | xcd;
    bn = s & 7;
  } else {
    bm = blockIdx.y; bn = blockIdx.x;
  }

  const int lr = lane & 15;           // fragment row/col within 16
  const int lk = (lane >> 4) << 3;    // k offset 0/8/16/24

  const ushort* gA_h = Ah + (size_t)(bm * 128) * K;
  const ushort* gA_l = SPLIT ? (Al + (size_t)(bm * 128) * K) : gA_h;
  const ushort* gB_h = Bh + (size_t)(bn * 128) * K;
  const ushort* gB_l = SPLIT ? (Bl + (size_t)(bn * 128) * K) : gB_h;

  f32x4 acc[4][4];
#pragma unroll
  for (int i = 0; i < 4; ++i)
#pragma unroll
    for (int j = 0; j < 4; ++j)
#pragma unroll
      for (int r = 0; r < 4; ++r) acc[i][j][r] = 0.f;

  auto stage = [&](int kt) {
    const int k0 = kt * 64;
#pragma unroll
    for (int i = 0; i < 4; ++i) {
      const int lin16 = i * 256 + t;          // 16B-chunk index, linear in LDS
      const int lb = lin16 << 4;              // LDS byte offset
      const int row = lb >> 7;                // 128B (=64 elems) per row
      const int srcb = (lb & 127) ^ ((row & 7) << 4);  // inverse swizzle on SOURCE
      const size_t goff = (size_t)row * K + (size_t)(k0 + (srcb >> 1));
      const int lidx = i * 2048 + w * 512;    // wave-uniform LDS base (ushort idx)
      gload_lds16(gA_h + goff, sAh + lidx);
      if (SPLIT) gload_lds16(gA_l + goff, sAl + lidx);
      gload_lds16(gB_h + goff, sBh + lidx);
      if (SPLIT) gload_lds16(gB_l + goff, sBl + lidx);
    }
  };

  auto ldfrag = [&](const ushort* s, int row, int kc) -> half8 {
    const int byte = (row << 7) + (((kc << 1) ^ ((row & 7) << 4)));
    return *reinterpret_cast<const half8*>(reinterpret_cast<const char*>(s) + byte);
  };

  const int NT = K / 64;
  stage(0);
  for (int kt = 0; kt < NT; ++kt) {
    __syncthreads();   // staged data visible (compiler drains vmcnt here)
#pragma unroll
    for (int kk = 0; kk < 2; ++kk) {
      half8 ah[4], bh[4], al[4], bl[4];
      const int kc = kk * 32 + lk;
#pragma unroll
      for (int i = 0; i < 4; ++i) {
        const int row = wm * 64 + i * 16 + lr;
        ah[i] = ldfrag(sAh, row, kc);
        if (SPLIT) al[i] = ldfrag(sAl, row, kc);
      }
#pragma unroll
      for (int j = 0; j < 4; ++j) {
        const int row = wn * 64 + j * 16 + lr;
        bh[j] = ldfrag(sBh, row, kc);
        if (SPLIT) bl[j] = ldfrag(sBl, row, kc);
      }
#pragma unroll
      for (int i = 0; i < 4; ++i)
#pragma unroll
        for (int j = 0; j < 4; ++j) {
          acc[i][j] = __builtin_amdgcn_mfma_f32_16x16x32_f16(ah[i], bh[j], acc[i][j], 0, 0, 0);
          if (SPLIT) {
            acc[i][j] = __builtin_amdgcn_mfma_f32_16x16x32_f16(al[i], bh[j], acc[i][j], 0, 0, 0);
            acc[i][j] = __builtin_amdgcn_mfma_f32_16x16x32_f16(ah[i], bl[j], acc[i][j], 0, 0, 0);
          }
        }
    }
    __syncthreads();   // all reads done before overwrite
    if (kt + 1 < NT) stage(kt + 1);
  }

  // Epilogue: C/D layout col=lane&15, row=(lane>>4)*4+reg  [m89]
  float* Cb = C + (size_t)(bm * 128) * N + bn * 128;
#pragma unroll
  for (int i = 0; i < 4; ++i)
#pragma unroll
    for (int j = 0; j < 4; ++j) {
      const int col = wn * 64 + j * 16 + lr;
      const float bv = bias[bn * 128 + col];
#pragma unroll
      for (int r = 0; r < 4; ++r) {
        const int rowt = wm * 64 + i * 16 + ((lane >> 4) << 2) + r;
        float o = acc[i][j][r] + bv;
        if (SCALE) o *= BX_SCALE;
        Cb[(size_t)rowt * N + col] = o;
      }
    }
}

// ---------------- sequential recurrence ----------------
// Bx2 holds BX_SCALE*(x@W_B^T + b_B). One chain per (b,d) channel; fp32
// state. Dependent path per step (5 ops):
//   fmaf(a2,h,bx) -> exp2 -> add 1 -> rcp -> fmaf(-2,r,1)
// No clamp: |u2| <= ~27 so exp2 cannot overflow, rcp(p+1) is NaN-free.
// Ping-pong double buffer (P=32 per buffer): each buffer's reload is issued
// right after its last use and hides under the other buffer's 32 compute
// steps (~1000 cyc vs ~900 cyc HBM latency) — no copy, no chunk-boundary
// vmcnt(0) stall on the critical path.
__global__ __launch_bounds__(64)
void k_recurrence(const float* __restrict__ Bx2, const float* __restrict__ Avec,
                  ushort* __restrict__ Hout) {
  const int tid = blockIdx.x * 64 + threadIdx.x;   // 0..8191
  const int b = tid >> 10;
  const int d = tid & 1023;
  const float a2 = BX_SCALE * Avec[d];
  const float* bx = Bx2 + (size_t)b * 2048 * 1024 + d;
  ushort* ho = Hout + (size_t)b * 2048 * 1024 + d;

  constexpr int P = 32;
  constexpr int NC = 2048 / P;   // 64 chunks, even
  float bufA[P], bufB[P];
#pragma unroll
  for (int i = 0; i < P; ++i) bufA[i] = bx[(size_t)i * 1024];
#pragma unroll
  for (int i = 0; i < P; ++i) bufB[i] = bx[(size_t)(P + i) * 1024];

  float h = 0.f;
  for (int c = 0; c < NC; c += 2) {
#pragma unroll
    for (int i = 0; i < P; ++i) {
      const float u2 = fmaf(a2, h, bufA[i]);
      const float p  = pexp(u2);
      const float r  = __builtin_amdgcn_rcpf(p + 1.f);
      h = fmaf(-2.f, r, 1.f);
      ho[(size_t)(c * P + i) * 1024] = f2h(h);
    }
    if (c + 2 < NC) {
#pragma unroll
      for (int i = 0; i < P; ++i) bufA[i] = bx[(size_t)((c + 2) * P + i) * 1024];
    }
#pragma unroll
    for (int i = 0; i < P; ++i) {
      const float u2 = fmaf(a2, h, bufB[i]);
      const float p  = pexp(u2);
      const float r  = __builtin_amdgcn_rcpf(p + 1.f);
      h = fmaf(-2.f, r, 1.f);
      ho[(size_t)((c + 1) * P + i) * 1024] = f2h(h);
    }
    if (c + 3 < NC) {
#pragma unroll
      for (int i = 0; i < P; ++i) bufB[i] = bx[(size_t)((c + 3) * P + i) * 1024];
    }
  }
}

// ---------------- launch ----------------
extern "C" void kernel_launch(void* const* d_in, const int* in_sizes, int n_in,
                              void* d_out, int out_size, void* d_ws, size_t ws_size,
                              hipStream_t stream) {
  const float* x   = (const float*)d_in[0];
  const float* A   = (const float*)d_in[1];
  const float* W_B = (const float*)d_in[2];
  const float* b_B = (const float*)d_in[3];
  const float* W_C = (const float*)d_in[4];
  const float* b_C = (const float*)d_in[5];
  float* y = (float*)d_out;

  const int Bsz = 8, L = 2048, D = 1024;
  const int M = Bsz * L;                       // 16384

  char* ws = (char*)d_ws;
  ushort* x_hi  = (ushort*)(ws);                        // 32MB fp16
  ushort* x_lo  = (ushort*)(ws + 33554432);             // 32MB fp16
  ushort* wb_hi = (ushort*)(ws + 67108864);             // 2MB
  ushort* wb_lo = (ushort*)(ws + 69206016);             // 2MB
  ushort* wc    = (ushort*)(ws + 71303168);             // 2MB
  float*  Bx    = (float*)(ws + 73400320);              // 64MB fp32 scaled
  ushort* h     = x_hi;                                 // alias (dead after GEMM1)

  k_split_convert<<<2048, 256, 0, stream>>>(x, x_hi, x_lo, M * D / 4);
  k_split_convert<<<512, 256, 0, stream>>>(W_B, wb_hi, wb_lo, D * D / 4);
  k_convert<<<512, 256, 0, stream>>>(W_C, wc, D * D / 4);

  k_gemm_bt<1, 1><<<dim3(D / 128, M / 128), 256, 0, stream>>>(
      x_hi, x_lo, wb_hi, wb_lo, b_B, Bx, M, D, D);

  k_recurrence<<<(Bsz * D) / 64, 64, 0, stream>>>(Bx, A, h);

  k_gemm_bt<0, 0><<<dim3(D / 128, M / 128), 256, 0, stream>>>(
      h, (const ushort*)nullptr, wc, (const ushort*)nullptr, b_C, y, M, D, D);
}